// Round 1
// baseline (737.903 us; speedup 1.0000x reference)
//
#include <hip/hip_runtime.h>
#include <hip/hip_bf16.h>

#define NPTS 8192
#define DDIM 128
#define MARGIN 0.2f
#define NEG_FLOOR 0.6f
#define SENT -1e30f

typedef __attribute__((ext_vector_type(8))) short short8;
typedef __attribute__((ext_vector_type(4))) float f32x4;

// ws layout (bytes):
//   [0, NPTS*DDIM*2)                      : bf16 X           (2 MiB)
//   A = NPTS*DDIM*2
//   [A, A+4*NPTS)                         : float max_pos
//   [A+4N, A+8N)                          : float max_neg
//   [A+8N, A+12N)                         : float row_loss
//   [A+12N, A+16N)                        : int   row_flag

__global__ __launch_bounds__(256) void k_convert(const float* __restrict__ x,
                                                 unsigned short* __restrict__ xb) {
    int i = blockIdx.x * 256 + threadIdx.x;  // grid covers NPTS*DDIM exactly
    unsigned u = __builtin_bit_cast(unsigned, x[i]);
    xb[i] = (unsigned short)((u + 0x7FFFu + ((u >> 16) & 1u)) >> 16);
}

__global__ __launch_bounds__(256) void k_pass1(const unsigned short* __restrict__ xb,
                                               const int* __restrict__ tg,
                                               float* __restrict__ maxpos,
                                               float* __restrict__ maxneg) {
    int lane = threadIdx.x & 63;
    int wv   = (blockIdx.x * 256 + threadIdx.x) >> 6;  // global wave id
    int i0   = wv * 16;
    int lr   = lane & 15;   // A-row within tile / B-col within tile
    int hi   = lane >> 4;   // k-group

    short8 a[4];
#pragma unroll
    for (int ks = 0; ks < 4; ++ks)
        a[ks] = *(const short8*)(xb + (i0 + lr) * DDIM + ks * 32 + hi * 8);

    int trow[4];
#pragma unroll
    for (int r = 0; r < 4; ++r) trow[r] = tg[i0 + hi * 4 + r];

    float mp[4], mn[4];
#pragma unroll
    for (int r = 0; r < 4; ++r) { mp[r] = SENT; mn[r] = SENT; }

    for (int j0 = 0; j0 < NPTS; j0 += 16) {
        f32x4 acc = {0.f, 0.f, 0.f, 0.f};
#pragma unroll
        for (int ks = 0; ks < 4; ++ks) {
            short8 b = *(const short8*)(xb + (j0 + lr) * DDIM + ks * 32 + hi * 8);
            acc = __builtin_amdgcn_mfma_f32_16x16x32_bf16(a[ks], b, acc, 0, 0, 0);
        }
        int tj = tg[j0 + lr];
#pragma unroll
        for (int r = 0; r < 4; ++r) {
            int row   = i0 + hi * 4 + r;
            bool same = (tj == trow[r]);
            bool diag = (j0 + lr) == row;
            float s   = acc[r];
            mp[r] = fmaxf(mp[r], (same && !diag) ? s : SENT);
            mn[r] = fmaxf(mn[r], same ? SENT : s);
        }
    }
#pragma unroll
    for (int off = 1; off < 16; off <<= 1) {
#pragma unroll
        for (int r = 0; r < 4; ++r) {
            mp[r] = fmaxf(mp[r], __shfl_xor(mp[r], off, 64));
            mn[r] = fmaxf(mn[r], __shfl_xor(mn[r], off, 64));
        }
    }
    if (lr == 0) {
#pragma unroll
        for (int r = 0; r < 4; ++r) {
            int row = i0 + hi * 4 + r;
            maxpos[row] = mp[r];
            maxneg[row] = mn[r];
        }
    }
}

__global__ __launch_bounds__(256) void k_pass2(const unsigned short* __restrict__ xb,
                                               const int* __restrict__ tg,
                                               const float* __restrict__ maxpos,
                                               const float* __restrict__ maxneg,
                                               float* __restrict__ rowloss,
                                               int* __restrict__ rowflag) {
    int lane = threadIdx.x & 63;
    int wv   = (blockIdx.x * 256 + threadIdx.x) >> 6;
    int i0   = wv * 16;
    int lr   = lane & 15;
    int hi   = lane >> 4;

    short8 a[4];
#pragma unroll
    for (int ks = 0; ks < 4; ++ks)
        a[ks] = *(const short8*)(xb + (i0 + lr) * DDIM + ks * 32 + hi * 8);

    int trow[4];
    float pos_lim[4], neg_th[4];
    bool hp[4];
#pragma unroll
    for (int r = 0; r < 4; ++r) {
        int row   = i0 + hi * 4 + r;
        trow[r]   = tg[row];
        float mpv = maxpos[row];
        float mnv = maxneg[row];
        pos_lim[r] = mnv + MARGIN;
        neg_th[r]  = fmaxf(NEG_FLOOR, mpv) - MARGIN;
        hp[r]      = mpv > -1e29f;
    }

    float sum[4] = {0.f, 0.f, 0.f, 0.f};
    int   an[4]  = {0, 0, 0, 0};

    for (int j0 = 0; j0 < NPTS; j0 += 16) {
        f32x4 acc = {0.f, 0.f, 0.f, 0.f};
#pragma unroll
        for (int ks = 0; ks < 4; ++ks) {
            short8 b = *(const short8*)(xb + (j0 + lr) * DDIM + ks * 32 + hi * 8);
            acc = __builtin_amdgcn_mfma_f32_16x16x32_bf16(a[ks], b, acc, 0, 0, 0);
        }
        int tj = tg[j0 + lr];
#pragma unroll
        for (int r = 0; r < 4; ++r) {
            int row   = i0 + hi * 4 + r;
            bool same = (tj == trow[r]);
            bool diag = (j0 + lr) == row;
            float s   = acc[r];
            bool psel = same && !diag && (s < pos_lim[r]);
            bool nsel = !same && (s > neg_th[r]);
            sum[r] += psel ? (1.0f - s) : 0.0f;
            sum[r] += nsel ? s : 0.0f;
            an[r]  |= (int)nsel;
        }
    }
#pragma unroll
    for (int off = 1; off < 16; off <<= 1) {
#pragma unroll
        for (int r = 0; r < 4; ++r) {
            sum[r] += __shfl_xor(sum[r], off, 64);
            an[r]  |= __shfl_xor(an[r], off, 64);
        }
    }
    if (lr == 0) {
#pragma unroll
        for (int r = 0; r < 4; ++r) {
            int row = i0 + hi * 4 + r;
            rowloss[row] = hp[r] ? sum[r] : 0.0f;
            rowflag[row] = (hp[r] && an[r]) ? 1 : 0;
        }
    }
}

__global__ __launch_bounds__(256) void k_final(const float* __restrict__ rowloss,
                                               const int* __restrict__ rowflag,
                                               float* __restrict__ out) {
    __shared__ float sf[256];
    __shared__ int   si[256];
    int t = threadIdx.x;
    float s = 0.f;
    int   c = 0;
    for (int i = t; i < NPTS; i += 256) { s += rowloss[i]; c += rowflag[i]; }
    sf[t] = s;
    si[t] = c;
    __syncthreads();
    for (int off = 128; off > 0; off >>= 1) {
        if (t < off) { sf[t] += sf[t + off]; si[t] += si[t + off]; }
        __syncthreads();
    }
    if (t == 0) {
        out[0] = sf[0] / (float)NPTS;
        out[1] = (float)si[0];
    }
}

extern "C" void kernel_launch(void* const* d_in, const int* in_sizes, int n_in,
                              void* d_out, int out_size, void* d_ws, size_t ws_size,
                              hipStream_t stream) {
    const float* x  = (const float*)d_in[0];
    const int*   tg = (const int*)d_in[1];
    float* out = (float*)d_out;

    unsigned short* xb = (unsigned short*)d_ws;
    char* base = (char*)d_ws + (size_t)NPTS * DDIM * 2;
    float* maxpos  = (float*)(base);
    float* maxneg  = (float*)(base + 4 * NPTS);
    float* rowloss = (float*)(base + 8 * NPTS);
    int*   rowflag = (int*)(base + 12 * NPTS);

    k_convert<<<(NPTS * DDIM) / 256, 256, 0, stream>>>(x, xb);
    k_pass1<<<NPTS / 64, 256, 0, stream>>>(xb, tg, maxpos, maxneg);
    k_pass2<<<NPTS / 64, 256, 0, stream>>>(xb, tg, maxpos, maxneg, rowloss, rowflag);
    k_final<<<1, 256, 0, stream>>>(rowloss, rowflag, out);
}

// Round 2
// 273.391 us; speedup vs baseline: 2.6991x; 2.6991x over previous
//
#include <hip/hip_runtime.h>
#include <hip/hip_bf16.h>

#define NPTS 8192
#define DDIM 128
#define MARGIN 0.2f
#define NEG_FLOOR 0.6f
#define SENT -1e30f
#define NCHUNK 16
#define CHUNK (NPTS / NCHUNK)   // 512

typedef __attribute__((ext_vector_type(8))) short short8;
typedef __attribute__((ext_vector_type(4))) float f32x4;
typedef __attribute__((ext_vector_type(4))) unsigned int uint4v;
typedef __attribute__((ext_vector_type(4))) unsigned short ushort4v;

// ws layout (bytes):
//   xb      : [0, 2 MiB)                       bf16 X
//   mp_part : 2MiB + [0, 512K)                 float [NCHUNK][NPTS]
//   mn_part : +512K                            float [NCHUNK][NPTS]
//   sum_part: +1M                              float [NCHUNK][NPTS]
//   flg_part: +1.5M                            int   [NCHUNK][NPTS]
//   maxpos  : +2M                              float [NPTS]
//   maxneg  : +2M+32K                          float [NPTS]

__device__ __forceinline__ unsigned short f2bf(unsigned u) {
    return (unsigned short)((u + 0x7FFFu + ((u >> 16) & 1u)) >> 16);
}

__global__ __launch_bounds__(256) void k_convert(const uint4v* __restrict__ x,
                                                 ushort4v* __restrict__ xb) {
    int i = blockIdx.x * 256 + threadIdx.x;  // NPTS*DDIM/4 elements
    uint4v u = x[i];
    ushort4v o;
    o.x = f2bf(u.x); o.y = f2bf(u.y); o.z = f2bf(u.z); o.w = f2bf(u.w);
    xb[i] = o;
}

__global__ __launch_bounds__(256) void k_pass1(const unsigned short* __restrict__ xb,
                                               const int* __restrict__ tg,
                                               float* __restrict__ mp_part,
                                               float* __restrict__ mn_part) {
    int lane  = threadIdx.x & 63;
    int wv    = (blockIdx.x * 256 + threadIdx.x) >> 6;  // [0, 8192)
    int chunk = wv & (NCHUNK - 1);
    int i0    = (wv >> 4) * 16;
    int lr    = lane & 15;
    int hi    = lane >> 4;

    short8 a[4];
#pragma unroll
    for (int ks = 0; ks < 4; ++ks)
        a[ks] = *(const short8*)(xb + (i0 + lr) * DDIM + ks * 32 + hi * 8);

    int trow[4];
#pragma unroll
    for (int r = 0; r < 4; ++r) trow[r] = tg[i0 + hi * 4 + r];

    float mp[4], mn[4];
#pragma unroll
    for (int r = 0; r < 4; ++r) { mp[r] = SENT; mn[r] = SENT; }

    int jbeg = chunk * CHUNK, jend = jbeg + CHUNK;
    for (int j0 = jbeg; j0 < jend; j0 += 32) {
        f32x4 acc0 = {0.f, 0.f, 0.f, 0.f};
        f32x4 acc1 = {0.f, 0.f, 0.f, 0.f};
        const unsigned short* b0p = xb + (j0 + lr) * DDIM + hi * 8;
        const unsigned short* b1p = b0p + 16 * DDIM;
#pragma unroll
        for (int ks = 0; ks < 4; ++ks) {
            short8 b0 = *(const short8*)(b0p + ks * 32);
            short8 b1 = *(const short8*)(b1p + ks * 32);
            acc0 = __builtin_amdgcn_mfma_f32_16x16x32_bf16(a[ks], b0, acc0, 0, 0, 0);
            acc1 = __builtin_amdgcn_mfma_f32_16x16x32_bf16(a[ks], b1, acc1, 0, 0, 0);
        }
        int tj0 = tg[j0 + lr];
        int tj1 = tg[j0 + 16 + lr];
#pragma unroll
        for (int r = 0; r < 4; ++r) {
            int row = i0 + hi * 4 + r;
            {
                bool same = (tj0 == trow[r]);
                bool diag = (j0 + lr) == row;
                float s = acc0[r];
                mp[r] = fmaxf(mp[r], (same && !diag) ? s : SENT);
                mn[r] = fmaxf(mn[r], same ? SENT : s);
            }
            {
                bool same = (tj1 == trow[r]);
                bool diag = (j0 + 16 + lr) == row;
                float s = acc1[r];
                mp[r] = fmaxf(mp[r], (same && !diag) ? s : SENT);
                mn[r] = fmaxf(mn[r], same ? SENT : s);
            }
        }
    }
#pragma unroll
    for (int off = 1; off < 16; off <<= 1) {
#pragma unroll
        for (int r = 0; r < 4; ++r) {
            mp[r] = fmaxf(mp[r], __shfl_xor(mp[r], off, 64));
            mn[r] = fmaxf(mn[r], __shfl_xor(mn[r], off, 64));
        }
    }
    if (lr == 0) {
#pragma unroll
        for (int r = 0; r < 4; ++r) {
            int row = i0 + hi * 4 + r;
            mp_part[chunk * NPTS + row] = mp[r];
            mn_part[chunk * NPTS + row] = mn[r];
        }
    }
}

__global__ __launch_bounds__(256) void k_red1(const float* __restrict__ mp_part,
                                              const float* __restrict__ mn_part,
                                              float* __restrict__ maxpos,
                                              float* __restrict__ maxneg) {
    int row = blockIdx.x * 256 + threadIdx.x;
    float mp = SENT, mn = SENT;
#pragma unroll
    for (int c = 0; c < NCHUNK; ++c) {
        mp = fmaxf(mp, mp_part[c * NPTS + row]);
        mn = fmaxf(mn, mn_part[c * NPTS + row]);
    }
    maxpos[row] = mp;
    maxneg[row] = mn;
}

__global__ __launch_bounds__(256) void k_pass2(const unsigned short* __restrict__ xb,
                                               const int* __restrict__ tg,
                                               const float* __restrict__ maxpos,
                                               const float* __restrict__ maxneg,
                                               float* __restrict__ sum_part,
                                               int* __restrict__ flg_part) {
    int lane  = threadIdx.x & 63;
    int wv    = (blockIdx.x * 256 + threadIdx.x) >> 6;
    int chunk = wv & (NCHUNK - 1);
    int i0    = (wv >> 4) * 16;
    int lr    = lane & 15;
    int hi    = lane >> 4;

    short8 a[4];
#pragma unroll
    for (int ks = 0; ks < 4; ++ks)
        a[ks] = *(const short8*)(xb + (i0 + lr) * DDIM + ks * 32 + hi * 8);

    int trow[4];
    float pos_lim[4], neg_th[4];
#pragma unroll
    for (int r = 0; r < 4; ++r) {
        int row    = i0 + hi * 4 + r;
        trow[r]    = tg[row];
        pos_lim[r] = maxneg[row] + MARGIN;
        neg_th[r]  = fmaxf(NEG_FLOOR, maxpos[row]) - MARGIN;
    }

    float sum[4] = {0.f, 0.f, 0.f, 0.f};
    int   an[4]  = {0, 0, 0, 0};

    int jbeg = chunk * CHUNK, jend = jbeg + CHUNK;
    for (int j0 = jbeg; j0 < jend; j0 += 32) {
        f32x4 acc0 = {0.f, 0.f, 0.f, 0.f};
        f32x4 acc1 = {0.f, 0.f, 0.f, 0.f};
        const unsigned short* b0p = xb + (j0 + lr) * DDIM + hi * 8;
        const unsigned short* b1p = b0p + 16 * DDIM;
#pragma unroll
        for (int ks = 0; ks < 4; ++ks) {
            short8 b0 = *(const short8*)(b0p + ks * 32);
            short8 b1 = *(const short8*)(b1p + ks * 32);
            acc0 = __builtin_amdgcn_mfma_f32_16x16x32_bf16(a[ks], b0, acc0, 0, 0, 0);
            acc1 = __builtin_amdgcn_mfma_f32_16x16x32_bf16(a[ks], b1, acc1, 0, 0, 0);
        }
        int tj0 = tg[j0 + lr];
        int tj1 = tg[j0 + 16 + lr];
#pragma unroll
        for (int r = 0; r < 4; ++r) {
            int row = i0 + hi * 4 + r;
            {
                bool same = (tj0 == trow[r]);
                bool diag = (j0 + lr) == row;
                float s = acc0[r];
                bool psel = same && !diag && (s < pos_lim[r]);
                bool nsel = !same && (s > neg_th[r]);
                sum[r] += psel ? (1.0f - s) : 0.0f;
                sum[r] += nsel ? s : 0.0f;
                an[r]  |= (int)nsel;
            }
            {
                bool same = (tj1 == trow[r]);
                bool diag = (j0 + 16 + lr) == row;
                float s = acc1[r];
                bool psel = same && !diag && (s < pos_lim[r]);
                bool nsel = !same && (s > neg_th[r]);
                sum[r] += psel ? (1.0f - s) : 0.0f;
                sum[r] += nsel ? s : 0.0f;
                an[r]  |= (int)nsel;
            }
        }
    }
#pragma unroll
    for (int off = 1; off < 16; off <<= 1) {
#pragma unroll
        for (int r = 0; r < 4; ++r) {
            sum[r] += __shfl_xor(sum[r], off, 64);
            an[r]  |= __shfl_xor(an[r], off, 64);
        }
    }
    if (lr == 0) {
#pragma unroll
        for (int r = 0; r < 4; ++r) {
            int row = i0 + hi * 4 + r;
            sum_part[chunk * NPTS + row] = sum[r];
            flg_part[chunk * NPTS + row] = an[r];
        }
    }
}

__global__ __launch_bounds__(256) void k_final(const float* __restrict__ maxpos,
                                               const float* __restrict__ sum_part,
                                               const int* __restrict__ flg_part,
                                               float* __restrict__ out) {
    __shared__ float sf[256];
    __shared__ int   si[256];
    int t = threadIdx.x;
    float s = 0.f;
    int   c = 0;
    for (int row = t; row < NPTS; row += 256) {
        bool hp = maxpos[row] > -1e29f;
        float rs = 0.f;
        int   fl = 0;
#pragma unroll
        for (int ch = 0; ch < NCHUNK; ++ch) {
            rs += sum_part[ch * NPTS + row];
            fl |= flg_part[ch * NPTS + row];
        }
        s += hp ? rs : 0.f;
        c += (hp && fl) ? 1 : 0;
    }
    sf[t] = s;
    si[t] = c;
    __syncthreads();
    for (int off = 128; off > 0; off >>= 1) {
        if (t < off) { sf[t] += sf[t + off]; si[t] += si[t + off]; }
        __syncthreads();
    }
    if (t == 0) {
        out[0] = sf[0] / (float)NPTS;
        out[1] = (float)si[0];
    }
}

extern "C" void kernel_launch(void* const* d_in, const int* in_sizes, int n_in,
                              void* d_out, int out_size, void* d_ws, size_t ws_size,
                              hipStream_t stream) {
    const float* x  = (const float*)d_in[0];
    const int*   tg = (const int*)d_in[1];
    float* out = (float*)d_out;

    unsigned short* xb = (unsigned short*)d_ws;
    char* base = (char*)d_ws + (size_t)NPTS * DDIM * 2;
    float* mp_part  = (float*)(base);
    float* mn_part  = (float*)(base + 1 * (NCHUNK * NPTS * 4));
    float* sum_part = (float*)(base + 2 * (NCHUNK * NPTS * 4));
    int*   flg_part = (int*)  (base + 3 * (NCHUNK * NPTS * 4));
    float* maxpos   = (float*)(base + 4 * (NCHUNK * NPTS * 4));
    float* maxneg   = (float*)(base + 4 * (NCHUNK * NPTS * 4) + NPTS * 4);

    k_convert<<<(NPTS * DDIM / 4) / 256, 256, 0, stream>>>((const uint4v*)x, (ushort4v*)xb);
    k_pass1<<<(NPTS / 16) * NCHUNK / 4, 256, 0, stream>>>(xb, tg, mp_part, mn_part);
    k_red1<<<NPTS / 256, 256, 0, stream>>>(mp_part, mn_part, maxpos, maxneg);
    k_pass2<<<(NPTS / 16) * NCHUNK / 4, 256, 0, stream>>>(xb, tg, maxpos, maxneg, sum_part, flg_part);
    k_final<<<1, 256, 0, stream>>>(maxpos, sum_part, flg_part, out);
}

// Round 3
// 161.925 us; speedup vs baseline: 4.5571x; 1.6884x over previous
//
#include <hip/hip_runtime.h>
#include <hip/hip_bf16.h>

#define NPTS 8192
#define DDIM 128
#define MARGIN 0.2f
#define NEG_FLOOR 0.6f
#define SENT -1e30f
#define NCHUNK 16
#define CHUNK (NPTS / NCHUNK)   // 512

typedef __attribute__((ext_vector_type(8))) short short8;
typedef __attribute__((ext_vector_type(4))) float f32x4;
typedef __attribute__((ext_vector_type(4))) unsigned int uint4v;
typedef __attribute__((ext_vector_type(4))) unsigned short ushort4v;

// ws layout (bytes):
//   xb      : [0, 2 MiB)                       bf16 X
//   mp_part : 2MiB + [0, 512K)                 float [NCHUNK][NPTS]
//   mn_part : +512K                            float [NCHUNK][NPTS]
//   sum_part: +1M                              float [NCHUNK][NPTS]
//   flg_part: +1.5M                            int   [NCHUNK][NPTS]
//   maxpos  : +2M                              float [NPTS]
//   maxneg  : +2M+32K                          float [NPTS]

__device__ __forceinline__ unsigned short f2bf(unsigned u) {
    return (unsigned short)((u + 0x7FFFu + ((u >> 16) & 1u)) >> 16);
}

__global__ __launch_bounds__(256) void k_convert(const uint4v* __restrict__ x,
                                                 ushort4v* __restrict__ xb) {
    int i = blockIdx.x * 256 + threadIdx.x;
    uint4v u = x[i];
    ushort4v o;
    o.x = f2bf(u.x); o.y = f2bf(u.y); o.z = f2bf(u.z); o.w = f2bf(u.w);
    xb[i] = o;
}

// 32 rows/wave (2 row-groups), 32 cols/iter (2 j-subtiles)
__global__ __launch_bounds__(256) void k_pass1(const unsigned short* __restrict__ xb,
                                               const int* __restrict__ tg,
                                               float* __restrict__ mp_part,
                                               float* __restrict__ mn_part) {
    int lane  = threadIdx.x & 63;
    int wv    = (blockIdx.x * 256 + threadIdx.x) >> 6;  // [0, 4096)
    int chunk = wv & (NCHUNK - 1);
    int i0    = (wv >> 4) * 32;
    int lr    = lane & 15;
    int hi    = lane >> 4;

    short8 a[2][4];
#pragma unroll
    for (int rg = 0; rg < 2; ++rg)
#pragma unroll
        for (int ks = 0; ks < 4; ++ks)
            a[rg][ks] = *(const short8*)(xb + (i0 + rg * 16 + lr) * DDIM + ks * 32 + hi * 8);

    int trow[2][4];
#pragma unroll
    for (int rg = 0; rg < 2; ++rg)
#pragma unroll
        for (int r = 0; r < 4; ++r)
            trow[rg][r] = tg[i0 + rg * 16 + hi * 4 + r];

    float mp[2][4], mn[2][4];
#pragma unroll
    for (int rg = 0; rg < 2; ++rg)
#pragma unroll
        for (int r = 0; r < 4; ++r) { mp[rg][r] = SENT; mn[rg][r] = SENT; }

    int jbeg = chunk * CHUNK, jend = jbeg + CHUNK;
    for (int j0 = jbeg; j0 < jend; j0 += 32) {
        int tj[2];
        short8 b[2][4];
#pragma unroll
        for (int jt = 0; jt < 2; ++jt) {
            tj[jt] = tg[j0 + jt * 16 + lr];
#pragma unroll
            for (int ks = 0; ks < 4; ++ks)
                b[jt][ks] = *(const short8*)(xb + (j0 + jt * 16 + lr) * DDIM + ks * 32 + hi * 8);
        }
        f32x4 acc[2][2] = {{{0.f,0.f,0.f,0.f},{0.f,0.f,0.f,0.f}},
                           {{0.f,0.f,0.f,0.f},{0.f,0.f,0.f,0.f}}};
#pragma unroll
        for (int ks = 0; ks < 4; ++ks)
#pragma unroll
            for (int rg = 0; rg < 2; ++rg)
#pragma unroll
                for (int jt = 0; jt < 2; ++jt)
                    acc[rg][jt] = __builtin_amdgcn_mfma_f32_16x16x32_bf16(a[rg][ks], b[jt][ks], acc[rg][jt], 0, 0, 0);
#pragma unroll
        for (int rg = 0; rg < 2; ++rg)
#pragma unroll
            for (int jt = 0; jt < 2; ++jt)
#pragma unroll
                for (int r = 0; r < 4; ++r) {
                    int row  = i0 + rg * 16 + hi * 4 + r;
                    int col  = j0 + jt * 16 + lr;
                    bool same = (tj[jt] == trow[rg][r]);
                    bool diag = (col == row);
                    float s   = acc[rg][jt][r];
                    mp[rg][r] = fmaxf(mp[rg][r], (same && !diag) ? s : SENT);
                    mn[rg][r] = fmaxf(mn[rg][r], same ? SENT : s);
                }
    }
#pragma unroll
    for (int off = 1; off < 16; off <<= 1)
#pragma unroll
        for (int rg = 0; rg < 2; ++rg)
#pragma unroll
            for (int r = 0; r < 4; ++r) {
                mp[rg][r] = fmaxf(mp[rg][r], __shfl_xor(mp[rg][r], off, 64));
                mn[rg][r] = fmaxf(mn[rg][r], __shfl_xor(mn[rg][r], off, 64));
            }
    if (lr == 0) {
#pragma unroll
        for (int rg = 0; rg < 2; ++rg)
#pragma unroll
            for (int r = 0; r < 4; ++r) {
                int row = i0 + rg * 16 + hi * 4 + r;
                mp_part[chunk * NPTS + row] = mp[rg][r];
                mn_part[chunk * NPTS + row] = mn[rg][r];
            }
    }
}

__global__ __launch_bounds__(256) void k_red1(const float* __restrict__ mp_part,
                                              const float* __restrict__ mn_part,
                                              float* __restrict__ maxpos,
                                              float* __restrict__ maxneg) {
    int row = blockIdx.x * 256 + threadIdx.x;
    float mp = SENT, mn = SENT;
#pragma unroll
    for (int c = 0; c < NCHUNK; ++c) {
        mp = fmaxf(mp, mp_part[c * NPTS + row]);
        mn = fmaxf(mn, mn_part[c * NPTS + row]);
    }
    maxpos[row] = mp;
    maxneg[row] = mn;
}

__global__ __launch_bounds__(256) void k_pass2(const unsigned short* __restrict__ xb,
                                               const int* __restrict__ tg,
                                               const float* __restrict__ maxpos,
                                               const float* __restrict__ maxneg,
                                               float* __restrict__ sum_part,
                                               int* __restrict__ flg_part) {
    int lane  = threadIdx.x & 63;
    int wv    = (blockIdx.x * 256 + threadIdx.x) >> 6;
    int chunk = wv & (NCHUNK - 1);
    int i0    = (wv >> 4) * 32;
    int lr    = lane & 15;
    int hi    = lane >> 4;

    short8 a[2][4];
#pragma unroll
    for (int rg = 0; rg < 2; ++rg)
#pragma unroll
        for (int ks = 0; ks < 4; ++ks)
            a[rg][ks] = *(const short8*)(xb + (i0 + rg * 16 + lr) * DDIM + ks * 32 + hi * 8);

    int trow[2][4];
    float pos_lim[2][4], neg_th[2][4];
#pragma unroll
    for (int rg = 0; rg < 2; ++rg)
#pragma unroll
        for (int r = 0; r < 4; ++r) {
            int row        = i0 + rg * 16 + hi * 4 + r;
            trow[rg][r]    = tg[row];
            pos_lim[rg][r] = maxneg[row] + MARGIN;
            neg_th[rg][r]  = fmaxf(NEG_FLOOR, maxpos[row]) - MARGIN;
        }

    float sum[2][4] = {{0.f,0.f,0.f,0.f},{0.f,0.f,0.f,0.f}};
    int   an = 0;   // bitmask: bit (rg*4+r)

    int jbeg = chunk * CHUNK, jend = jbeg + CHUNK;
    for (int j0 = jbeg; j0 < jend; j0 += 32) {
        int tj[2];
        short8 b[2][4];
#pragma unroll
        for (int jt = 0; jt < 2; ++jt) {
            tj[jt] = tg[j0 + jt * 16 + lr];
#pragma unroll
            for (int ks = 0; ks < 4; ++ks)
                b[jt][ks] = *(const short8*)(xb + (j0 + jt * 16 + lr) * DDIM + ks * 32 + hi * 8);
        }
        f32x4 acc[2][2] = {{{0.f,0.f,0.f,0.f},{0.f,0.f,0.f,0.f}},
                           {{0.f,0.f,0.f,0.f},{0.f,0.f,0.f,0.f}}};
#pragma unroll
        for (int ks = 0; ks < 4; ++ks)
#pragma unroll
            for (int rg = 0; rg < 2; ++rg)
#pragma unroll
                for (int jt = 0; jt < 2; ++jt)
                    acc[rg][jt] = __builtin_amdgcn_mfma_f32_16x16x32_bf16(a[rg][ks], b[jt][ks], acc[rg][jt], 0, 0, 0);
#pragma unroll
        for (int rg = 0; rg < 2; ++rg)
#pragma unroll
            for (int jt = 0; jt < 2; ++jt)
#pragma unroll
                for (int r = 0; r < 4; ++r) {
                    int row  = i0 + rg * 16 + hi * 4 + r;
                    int col  = j0 + jt * 16 + lr;
                    bool same = (tj[jt] == trow[rg][r]);
                    bool diag = (col == row);
                    float s   = acc[rg][jt][r];
                    bool psel = same && !diag && (s < pos_lim[rg][r]);
                    bool nsel = !same && (s > neg_th[rg][r]);
                    float contrib = psel ? (1.0f - s) : (nsel ? s : 0.0f);
                    sum[rg][r] += contrib;
                    an |= nsel ? (1 << (rg * 4 + r)) : 0;
                }
    }
#pragma unroll
    for (int off = 1; off < 16; off <<= 1) {
        an |= __shfl_xor(an, off, 64);
#pragma unroll
        for (int rg = 0; rg < 2; ++rg)
#pragma unroll
            for (int r = 0; r < 4; ++r)
                sum[rg][r] += __shfl_xor(sum[rg][r], off, 64);
    }
    if (lr == 0) {
#pragma unroll
        for (int rg = 0; rg < 2; ++rg)
#pragma unroll
            for (int r = 0; r < 4; ++r) {
                int row = i0 + rg * 16 + hi * 4 + r;
                sum_part[chunk * NPTS + row] = sum[rg][r];
                flg_part[chunk * NPTS + row] = (an >> (rg * 4 + r)) & 1;
            }
    }
}

__global__ __launch_bounds__(256) void k_final(const float* __restrict__ maxpos,
                                               const float* __restrict__ sum_part,
                                               const int* __restrict__ flg_part,
                                               float* __restrict__ out) {
    __shared__ float sf[256];
    __shared__ int   si[256];
    int t = threadIdx.x;
    float s = 0.f;
    int   c = 0;
    for (int row = t; row < NPTS; row += 256) {
        bool hp = maxpos[row] > -1e29f;
        float rs = 0.f;
        int   fl = 0;
#pragma unroll
        for (int ch = 0; ch < NCHUNK; ++ch) {
            rs += sum_part[ch * NPTS + row];
            fl |= flg_part[ch * NPTS + row];
        }
        s += hp ? rs : 0.f;
        c += (hp && fl) ? 1 : 0;
    }
    sf[t] = s;
    si[t] = c;
    __syncthreads();
    for (int off = 128; off > 0; off >>= 1) {
        if (t < off) { sf[t] += sf[t + off]; si[t] += si[t + off]; }
        __syncthreads();
    }
    if (t == 0) {
        out[0] = sf[0] / (float)NPTS;
        out[1] = (float)si[0];
    }
}

extern "C" void kernel_launch(void* const* d_in, const int* in_sizes, int n_in,
                              void* d_out, int out_size, void* d_ws, size_t ws_size,
                              hipStream_t stream) {
    const float* x  = (const float*)d_in[0];
    const int*   tg = (const int*)d_in[1];
    float* out = (float*)d_out;

    unsigned short* xb = (unsigned short*)d_ws;
    char* base = (char*)d_ws + (size_t)NPTS * DDIM * 2;
    float* mp_part  = (float*)(base);
    float* mn_part  = (float*)(base + 1 * (NCHUNK * NPTS * 4));
    float* sum_part = (float*)(base + 2 * (NCHUNK * NPTS * 4));
    int*   flg_part = (int*)  (base + 3 * (NCHUNK * NPTS * 4));
    float* maxpos   = (float*)(base + 4 * (NCHUNK * NPTS * 4));
    float* maxneg   = (float*)(base + 4 * (NCHUNK * NPTS * 4) + NPTS * 4);

    k_convert<<<(NPTS * DDIM / 4) / 256, 256, 0, stream>>>((const uint4v*)x, (ushort4v*)xb);
    k_pass1<<<(NPTS / 32) * NCHUNK / 4, 256, 0, stream>>>(xb, tg, mp_part, mn_part);
    k_red1<<<NPTS / 256, 256, 0, stream>>>(mp_part, mn_part, maxpos, maxneg);
    k_pass2<<<(NPTS / 32) * NCHUNK / 4, 256, 0, stream>>>(xb, tg, maxpos, maxneg, sum_part, flg_part);
    k_final<<<1, 256, 0, stream>>>(maxpos, sum_part, flg_part, out);
}